// Round 3
// baseline (110.205 us; speedup 1.0000x reference)
//
#include <hip/hip_runtime.h>
#include <hip/hip_cooperative_groups.h>

namespace cg = cooperative_groups;

#define FAPE_EPS   1e-4f
#define FAPE_CLAMP 10.0f
#define FAPE_Z     10.0f

constexpr int TPB   = 256;        // threads per block
constexpr int FPB   = 8;          // frames per block
constexpr int APT   = 4;          // atoms per thread
constexpr int ATILE = TPB * APT;  // 1024 atoms per block tile

// Block reduce; result valid on tid==0. swave is TPB/64 floats.
__device__ __forceinline__ float blockReduce(float v, float* swave, int tid) {
    for (int off = 32; off > 0; off >>= 1) v += __shfl_down(v, off);
    if ((tid & 63) == 0) swave[tid >> 6] = v;
    __syncthreads();
    float s = 0.f;
    if (tid == 0) {
#pragma unroll
        for (int w = 0; w < TPB / 64; ++w) s += swave[w];
    }
    __syncthreads();   // swave reusable afterwards
    return s;
}

// Single cooperative kernel:
//  phase 1: each block = (batch, frame-tile, atom-tile); atoms loaded once as
//           float4 into registers, reused across FPB frames; per-block partial
//           sums written to ws (own slot, no init required). Blocks with
//           ftile==0 also write a mask partial per atom tile.
//  grid sync
//  phase 2: block `batch` (< b) reduces its partials + mask partials, writes out.
__global__ __launch_bounds__(TPB) void fape_fused_kernel(
        const float* __restrict__ Rp, const float* __restrict__ tp,
        const float* __restrict__ pp, const float* __restrict__ mask,
        const float* __restrict__ Rt, const float* __restrict__ tt,
        const float* __restrict__ pt, float* __restrict__ out,
        float* __restrict__ ws, int N, int A,
        int fTilesPerBatch, int atomTiles, int b) {

    const int tid   = threadIdx.x;
    const int t     = blockIdx.x;
    const int atile = t % atomTiles;
    const int ft    = t / atomTiles;
    const int batch = ft / fTilesPerBatch;
    const int ftile = ft % fTilesPerBatch;
    const int f0    = ftile * FPB;

    float* __restrict__ partial  = ws;                 // [gridDim.x]
    float* __restrict__ maskPart = ws + gridDim.x;     // [b * atomTiles]

    const float* __restrict__ ppb = pp   + (size_t)batch * A * 3;
    const float* __restrict__ ptb = pt   + (size_t)batch * A * 3;
    const float* __restrict__ mb  = mask + (size_t)batch * A;

    // ---- load APT atoms into registers (7 x float4) ----
    float p[APT][3], q[APT][3], m[APT];
    const int j0 = atile * ATILE + tid * APT;
    if (j0 + APT <= A) {
        const float4* p4 = reinterpret_cast<const float4*>(ppb + (size_t)j0 * 3);
        const float4* q4 = reinterpret_cast<const float4*>(ptb + (size_t)j0 * 3);
        const float4  P0 = p4[0], P1 = p4[1], P2 = p4[2];
        const float4  Q0 = q4[0], Q1 = q4[1], Q2 = q4[2];
        const float4  M  = *reinterpret_cast<const float4*>(mb + j0);
        p[0][0]=P0.x; p[0][1]=P0.y; p[0][2]=P0.z;
        p[1][0]=P0.w; p[1][1]=P1.x; p[1][2]=P1.y;
        p[2][0]=P1.z; p[2][1]=P1.w; p[2][2]=P2.x;
        p[3][0]=P2.y; p[3][1]=P2.z; p[3][2]=P2.w;
        q[0][0]=Q0.x; q[0][1]=Q0.y; q[0][2]=Q0.z;
        q[1][0]=Q0.w; q[1][1]=Q1.x; q[1][2]=Q1.y;
        q[2][0]=Q1.z; q[2][1]=Q1.w; q[2][2]=Q2.x;
        q[3][0]=Q2.y; q[3][1]=Q2.z; q[3][2]=Q2.w;
        m[0]=M.x; m[1]=M.y; m[2]=M.z; m[3]=M.w;
    } else {
#pragma unroll
        for (int k = 0; k < APT; ++k) {
            const int j = j0 + k;
            if (j < A) {
                p[k][0]=ppb[j*3+0]; p[k][1]=ppb[j*3+1]; p[k][2]=ppb[j*3+2];
                q[k][0]=ptb[j*3+0]; q[k][1]=ptb[j*3+1]; q[k][2]=ptb[j*3+2];
                m[k]=mb[j];
            } else {
                p[k][0]=p[k][1]=p[k][2]=0.f;
                q[k][0]=q[k][1]=q[k][2]=0.f;
                m[k]=0.f;
            }
        }
    }

    float local = 0.0f;
#pragma unroll
    for (int f = 0; f < FPB; ++f) {
        const int fl = f0 + f;
        if (fl < N) {
            const size_t fi = (size_t)batch * N + fl;   // block-uniform
            const float* __restrict__ rp = Rp + fi * 9;
            const float* __restrict__ rt = Rt + fi * 9;
            const float* __restrict__ tv = tp + fi * 3;
            const float* __restrict__ uv = tt + fi * 3;

            const float rp00=rp[0], rp01=rp[1], rp02=rp[2];
            const float rp10=rp[3], rp11=rp[4], rp12=rp[5];
            const float rp20=rp[6], rp21=rp[7], rp22=rp[8];
            const float rt00=rt[0], rt01=rt[1], rt02=rt[2];
            const float rt10=rt[3], rt11=rt[4], rt12=rt[5];
            const float rt20=rt[6], rt21=rt[7], rt22=rt[8];
            const float tp0=tv[0], tp1=tv[1], tp2=tv[2];
            const float tt0=uv[0], tt1=uv[1], tt2=uv[2];

            // c = Rt^T t_t - Rp^T t_p
            const float c0 = rt00*tt0 + rt10*tt1 + rt20*tt2 - (rp00*tp0 + rp10*tp1 + rp20*tp2);
            const float c1 = rt01*tt0 + rt11*tt1 + rt21*tt2 - (rp01*tp0 + rp11*tp1 + rp21*tp2);
            const float c2 = rt02*tt0 + rt12*tt1 + rt22*tt2 - (rp02*tp0 + rp12*tp1 + rp22*tp2);

#pragma unroll
            for (int k = 0; k < APT; ++k) {
                float x0 = c0 + rp00*p[k][0] + rp10*p[k][1] + rp20*p[k][2]
                              - rt00*q[k][0] - rt10*q[k][1] - rt20*q[k][2];
                float x1 = c1 + rp01*p[k][0] + rp11*p[k][1] + rp21*p[k][2]
                              - rt01*q[k][0] - rt11*q[k][1] - rt21*q[k][2];
                float x2 = c2 + rp02*p[k][0] + rp12*p[k][1] + rp22*p[k][2]
                              - rt02*q[k][0] - rt12*q[k][1] - rt22*q[k][2];
                const float d = __builtin_amdgcn_sqrtf(x0*x0 + x1*x1 + x2*x2 + FAPE_EPS);
                local += fminf(d, FAPE_CLAMP) * m[k];
            }
        }
    }

    __shared__ float swave[TPB / 64];
    {
        const float bs = blockReduce(local, swave, tid);
        if (tid == 0) partial[t] = bs;
    }
    if (ftile == 0) {                       // block-uniform condition
        const float mbs = blockReduce(m[0] + m[1] + m[2] + m[3], swave, tid);
        if (tid == 0) maskPart[batch * atomTiles + atile] = mbs;
    }

    cg::this_grid().sync();

    // ---- phase 2: first b blocks finalize ----
    if (t < b) {
        const int P = fTilesPerBatch * atomTiles;
        float s = 0.f;
        for (int i = tid; i < P; i += TPB) s += partial[t * P + i];
        const float sb = blockReduce(s, swave, tid);

        const float mv  = (tid < atomTiles) ? maskPart[t * atomTiles + tid] : 0.f;
        const float msb = blockReduce(mv, swave, tid);

        if (tid == 0)
            out[t] = sb / (fmaxf(msb, 1.0f) * (float)N * FAPE_Z);
    }
}

extern "C" void kernel_launch(void* const* d_in, const int* in_sizes, int n_in,
                              void* d_out, int out_size, void* d_ws, size_t ws_size,
                              hipStream_t stream) {
    const float* Rp   = (const float*)d_in[0];  // [b,N,3,3]
    const float* tp   = (const float*)d_in[1];  // [b,N,3]
    const float* pp   = (const float*)d_in[2];  // [b,N,14,3]
    const float* mask = (const float*)d_in[3];  // [b,N,14]
    const float* Rt   = (const float*)d_in[4];
    const float* tt   = (const float*)d_in[5];
    const float* pt   = (const float*)d_in[6];
    float* out = (float*)d_out;
    float* ws  = (float*)d_ws;

    int b  = out_size;
    int bN = in_sizes[1] / 3;
    int N  = bN / b;
    int A  = N * 14;

    int fTilesPerBatch = (N + FPB - 1) / FPB;
    int atomTiles      = (A + ATILE - 1) / ATILE;
    int nBlocks        = b * fTilesPerBatch * atomTiles;

    void* kargs[] = {
        (void*)&Rp, (void*)&tp, (void*)&pp, (void*)&mask,
        (void*)&Rt, (void*)&tt, (void*)&pt, (void*)&out,
        (void*)&ws, (void*)&N, (void*)&A,
        (void*)&fTilesPerBatch, (void*)&atomTiles, (void*)&b
    };
    hipLaunchCooperativeKernel((const void*)fape_fused_kernel,
                               dim3(nBlocks), dim3(TPB), kargs, 0, stream);
}

// Round 4
// 18.488 us; speedup vs baseline: 5.9609x; 5.9609x over previous
//
#include <hip/hip_runtime.h>

#define FAPE_EPS   1e-4f
#define FAPE_CLAMP 10.0f
#define FAPE_Z     10.0f

constexpr int TPB   = 256;        // threads per block
constexpr int FPB   = 8;          // frames per block
constexpr int APT   = 4;          // atoms per thread
constexpr int ATILE = TPB * APT;  // 1024 atoms per block tile

__device__ __forceinline__ float blockReduce(float v, float* swave, int tid) {
    for (int off = 32; off > 0; off >>= 1) v += __shfl_down(v, off);
    if ((tid & 63) == 0) swave[tid >> 6] = v;
    __syncthreads();
    float s = 0.f;
    if (tid == 0) {
#pragma unroll
        for (int w = 0; w < TPB / 64; ++w) s += swave[w];
    }
    return s;
}

// Kernel A: block = (batch, frame-tile, atom-tile). Atoms loaded once per
// thread as float4s into registers, reused across FPB frames. Per-block
// partial written to its OWN slot in ws (written-before-read every replay,
// so no init / no atomics needed).
__global__ __launch_bounds__(TPB) void fape_frames_kernel(
        const float* __restrict__ Rp, const float* __restrict__ tp,
        const float* __restrict__ pp, const float* __restrict__ mask,
        const float* __restrict__ Rt, const float* __restrict__ tt,
        const float* __restrict__ pt, float* __restrict__ partial,
        int N, int A, int fTilesPerBatch, int atomTiles) {

    const int tid   = threadIdx.x;
    const int t     = blockIdx.x;
    const int atile = t % atomTiles;
    const int ft    = t / atomTiles;
    const int batch = ft / fTilesPerBatch;
    const int f0    = (ft % fTilesPerBatch) * FPB;

    const float* __restrict__ ppb = pp   + (size_t)batch * A * 3;
    const float* __restrict__ ptb = pt   + (size_t)batch * A * 3;
    const float* __restrict__ mb  = mask + (size_t)batch * A;

    // ---- load APT atoms into registers (7 x float4) ----
    float p[APT][3], q[APT][3], m[APT];
    const int j0 = atile * ATILE + tid * APT;
    if (j0 + APT <= A) {
        const float4* p4 = reinterpret_cast<const float4*>(ppb + (size_t)j0 * 3);
        const float4* q4 = reinterpret_cast<const float4*>(ptb + (size_t)j0 * 3);
        const float4  P0 = p4[0], P1 = p4[1], P2 = p4[2];
        const float4  Q0 = q4[0], Q1 = q4[1], Q2 = q4[2];
        const float4  M  = *reinterpret_cast<const float4*>(mb + j0);
        p[0][0]=P0.x; p[0][1]=P0.y; p[0][2]=P0.z;
        p[1][0]=P0.w; p[1][1]=P1.x; p[1][2]=P1.y;
        p[2][0]=P1.z; p[2][1]=P1.w; p[2][2]=P2.x;
        p[3][0]=P2.y; p[3][1]=P2.z; p[3][2]=P2.w;
        q[0][0]=Q0.x; q[0][1]=Q0.y; q[0][2]=Q0.z;
        q[1][0]=Q0.w; q[1][1]=Q1.x; q[1][2]=Q1.y;
        q[2][0]=Q1.z; q[2][1]=Q1.w; q[2][2]=Q2.x;
        q[3][0]=Q2.y; q[3][1]=Q2.z; q[3][2]=Q2.w;
        m[0]=M.x; m[1]=M.y; m[2]=M.z; m[3]=M.w;
    } else {
#pragma unroll
        for (int k = 0; k < APT; ++k) {
            const int j = j0 + k;
            if (j < A) {
                p[k][0]=ppb[j*3+0]; p[k][1]=ppb[j*3+1]; p[k][2]=ppb[j*3+2];
                q[k][0]=ptb[j*3+0]; q[k][1]=ptb[j*3+1]; q[k][2]=ptb[j*3+2];
                m[k]=mb[j];
            } else {
                p[k][0]=p[k][1]=p[k][2]=0.f;
                q[k][0]=q[k][1]=q[k][2]=0.f;
                m[k]=0.f;
            }
        }
    }

    float local = 0.0f;
#pragma unroll
    for (int f = 0; f < FPB; ++f) {
        const int fl = f0 + f;
        if (fl < N) {
            const size_t fi = (size_t)batch * N + fl;   // block-uniform
            const float* __restrict__ rp = Rp + fi * 9;
            const float* __restrict__ rt = Rt + fi * 9;
            const float* __restrict__ tv = tp + fi * 3;
            const float* __restrict__ uv = tt + fi * 3;

            const float rp00=rp[0], rp01=rp[1], rp02=rp[2];
            const float rp10=rp[3], rp11=rp[4], rp12=rp[5];
            const float rp20=rp[6], rp21=rp[7], rp22=rp[8];
            const float rt00=rt[0], rt01=rt[1], rt02=rt[2];
            const float rt10=rt[3], rt11=rt[4], rt12=rt[5];
            const float rt20=rt[6], rt21=rt[7], rt22=rt[8];
            const float tp0=tv[0], tp1=tv[1], tp2=tv[2];
            const float tt0=uv[0], tt1=uv[1], tt2=uv[2];

            // c = Rt^T t_t - Rp^T t_p
            const float c0 = rt00*tt0 + rt10*tt1 + rt20*tt2 - (rp00*tp0 + rp10*tp1 + rp20*tp2);
            const float c1 = rt01*tt0 + rt11*tt1 + rt21*tt2 - (rp01*tp0 + rp11*tp1 + rp21*tp2);
            const float c2 = rt02*tt0 + rt12*tt1 + rt22*tt2 - (rp02*tp0 + rp12*tp1 + rp22*tp2);

#pragma unroll
            for (int k = 0; k < APT; ++k) {
                float x0 = c0 + rp00*p[k][0] + rp10*p[k][1] + rp20*p[k][2]
                              - rt00*q[k][0] - rt10*q[k][1] - rt20*q[k][2];
                float x1 = c1 + rp01*p[k][0] + rp11*p[k][1] + rp21*p[k][2]
                              - rt01*q[k][0] - rt11*q[k][1] - rt21*q[k][2];
                float x2 = c2 + rp02*p[k][0] + rp12*p[k][1] + rp22*p[k][2]
                              - rt02*q[k][0] - rt12*q[k][1] - rt22*q[k][2];
                const float d = __builtin_amdgcn_sqrtf(x0*x0 + x1*x1 + x2*x2 + FAPE_EPS);
                local += fminf(d, FAPE_CLAMP) * m[k];
            }
        }
    }

    __shared__ float swave[TPB / 64];
    const float bs = blockReduce(local, swave, tid);
    if (tid == 0) partial[t] = bs;
}

// Kernel B: one block per batch. Reduces this batch's P partials and the
// mask (float4 loads from global), writes out[batch].
__global__ __launch_bounds__(TPB) void fape_finalize_kernel(
        const float* __restrict__ mask, const float* __restrict__ partial,
        float* __restrict__ out, int N, int A, int P) {
    const int batch = blockIdx.x;
    const int tid   = threadIdx.x;

    float s = 0.f;
    const float* __restrict__ pb = partial + (size_t)batch * P;
    for (int i = tid; i < P; i += TPB) s += pb[i];

    float ms = 0.f;
    const float* __restrict__ mb = mask + (size_t)batch * A;
    const int A4 = A & ~3;
    for (int j = tid * 4; j + 4 <= A4; j += TPB * 4) {
        const float4 M = *reinterpret_cast<const float4*>(mb + j);
        ms += M.x + M.y + M.z + M.w;
    }
    for (int j = A4 + tid; j < A; j += TPB) ms += mb[j];

    __shared__ float swave[TPB / 64];
    const float sb = blockReduce(s, swave, tid);
    __syncthreads();
    const float msb = blockReduce(ms, swave, tid);

    if (tid == 0)
        out[batch] = sb / (fmaxf(msb, 1.0f) * (float)N * FAPE_Z);
}

extern "C" void kernel_launch(void* const* d_in, const int* in_sizes, int n_in,
                              void* d_out, int out_size, void* d_ws, size_t ws_size,
                              hipStream_t stream) {
    const float* Rp   = (const float*)d_in[0];  // [b,N,3,3]
    const float* tp   = (const float*)d_in[1];  // [b,N,3]
    const float* pp   = (const float*)d_in[2];  // [b,N,14,3]
    const float* mask = (const float*)d_in[3];  // [b,N,14]
    const float* Rt   = (const float*)d_in[4];
    const float* tt   = (const float*)d_in[5];
    const float* pt   = (const float*)d_in[6];
    float* out = (float*)d_out;
    float* ws  = (float*)d_ws;

    const int b  = out_size;
    const int bN = in_sizes[1] / 3;
    const int N  = bN / b;
    const int A  = N * 14;

    const int fTilesPerBatch = (N + FPB - 1) / FPB;
    const int atomTiles      = (A + ATILE - 1) / ATILE;
    const int P              = fTilesPerBatch * atomTiles;  // partials per batch
    const int nBlocks        = b * P;

    fape_frames_kernel<<<dim3(nBlocks), dim3(TPB), 0, stream>>>(
        Rp, tp, pp, mask, Rt, tt, pt, ws, N, A, fTilesPerBatch, atomTiles);
    fape_finalize_kernel<<<dim3(b), dim3(TPB), 0, stream>>>(
        mask, ws, out, N, A, P);
}